// Round 13
// baseline (253.803 us; speedup 1.0000x reference)
//
#include <hip/hip_runtime.h>
#include <hip/hip_bf16.h>

#define N_GRAPHS 64

typedef float f32x4 __attribute__((ext_vector_type(4)));
typedef short bf16x8 __attribute__((ext_vector_type(8)));

__device__ inline unsigned short f2bf(float f) {   // fp32 -> bf16 RNE
    unsigned int u = __float_as_uint(f);
    u = u + 0x7fffu + ((u >> 16) & 1u);
    return (unsigned short)(u >> 16);
}
__device__ inline float bf2f(unsigned short h) {
    return __uint_as_float(((unsigned int)h) << 16);
}

// ---------------------------------------------------------------------------
__global__ void k_deg(const int* __restrict__ dst, int E, int* __restrict__ deg) {
    int i = blockIdx.x * blockDim.x + threadIdx.x;
    if (i < E) atomicAdd(&deg[dst[i]], 1);
}

__global__ void k_dis_bsum(const int* __restrict__ deg, const float* __restrict__ x,
                           float* __restrict__ dis, float* __restrict__ xp,
                           int* __restrict__ bsum, int N) {
    int i = blockIdx.x * 256 + threadIdx.x;
    int dv = (i < N) ? deg[i] : 0;
    if (i < N) {
        float d = rsqrtf((float)(dv + 1));
        dis[i] = d;
        xp[i]  = d * x[i];
    }
    int v = dv;
#pragma unroll
    for (int o = 1; o < 64; o <<= 1) v += __shfl_xor(v, o);
    __shared__ int ws4[4];
    if ((threadIdx.x & 63) == 0) ws4[threadIdx.x >> 6] = v;
    __syncthreads();
    if (threadIdx.x == 0) bsum[blockIdx.x] = ws4[0] + ws4[1] + ws4[2] + ws4[3];
}

__device__ inline int block_scan_inc(int v, int* wsum) {
    int lane = threadIdx.x & 63, w = threadIdx.x >> 6;
    int iv = v;
#pragma unroll
    for (int o = 1; o < 64; o <<= 1) {
        int t = __shfl_up(iv, o);
        if (lane >= o) iv += t;
    }
    if (lane == 63) wsum[w] = iv;
    __syncthreads();
    int add = 0;
    for (int k = 0; k < w; ++k) add += wsum[k];
    return iv + add;
}

__global__ void k_scan_sums(const int* __restrict__ bsum, int nb, int* __restrict__ boff) {
    __shared__ int wsum[4];
    int tid = threadIdx.x;
    int v = (tid < nb) ? bsum[tid] : 0;
    int inc = block_scan_inc(v, wsum);
    if (tid < nb) boff[tid] = inc - v;
}

// also seeds fill[i] = row_ptr[i] so scatter needs no zeroed counter array
__global__ void k_scan_apply(const int* __restrict__ deg, const int* __restrict__ boff,
                             int* __restrict__ row_ptr, int* __restrict__ fill, int N) {
    __shared__ int wsum[4];
    int b = blockIdx.x, i = b * 256 + threadIdx.x;
    int v = (i < N) ? deg[i] : 0;
    int inc = block_scan_inc(v, wsum) + boff[b];
    if (i < N) {
        int ex = inc - v;
        row_ptr[i] = ex;
        fill[i] = ex;
        if (i == N - 1) row_ptr[N] = inc;
    }
}

// fill[d] holds the absolute write cursor (seeded from row_ptr)
__global__ void k_scatter(const int* __restrict__ src, const int* __restrict__ dst, int E,
                          int* __restrict__ fill, int* __restrict__ csr_src) {
    int e = blockIdx.x * blockDim.x + threadIdx.x;
    if (e < E) {
        int s = src[e];
        int pos = atomicAdd(&fill[dst[e]], 1);
        __builtin_nontemporal_store(s, &csr_src[pos]);
    }
}

// td2[d] = ( dis[d] * (sum xp[s] + xp[d]),  dis[d] )
__global__ void k_agg_scalar(const float* __restrict__ xp, const float* __restrict__ dis,
                             const int* __restrict__ row_ptr, const int* __restrict__ csr,
                             float2* __restrict__ td2, int N) {
    int d = blockIdx.x * blockDim.x + threadIdx.x;
    if (d >= N) return;
    float acc = xp[d];
    int e0 = row_ptr[d], e1 = row_ptr[d + 1];
    int e = e0;
    for (; e + 8 <= e1; e += 8) {
        int s0 = csr[e],     s1 = csr[e + 1], s2 = csr[e + 2], s3 = csr[e + 3];
        int s4 = csr[e + 4], s5 = csr[e + 5], s6 = csr[e + 6], s7 = csr[e + 7];
        acc += ((xp[s0] + xp[s1]) + (xp[s2] + xp[s3]))
             + ((xp[s4] + xp[s5]) + (xp[s6] + xp[s7]));
    }
    for (; e < e1; ++e) acc += xp[csr[e]];
    float dd = dis[d];
    td2[d] = make_float2(dd * acc, dd);
}

// ---------------------------------------------------------------------------
// Layer-2 aggregation with rank-1 h1 recompute (LDS-free, high occupancy)
__global__ void k_h1agg(const float2* __restrict__ td2,
                        const float4* __restrict__ W1f4, const float4* __restrict__ b1f4,
                        const int* __restrict__ row_ptr, const int* __restrict__ csr,
                        float4* __restrict__ out4, int N) {
    int node = blockIdx.x * 8 + (threadIdx.x >> 5);
    int lane = threadIdx.x & 31;
    if (node >= N) return;
    const float4 w1 = W1f4[lane];
    const float4 bv = b1f4[lane];
    float2 sv = td2[node];
    float dd = sv.y;
    float a0 = dd * fmaxf(fmaf(sv.x, w1.x, bv.x), 0.f);
    float a1 = dd * fmaxf(fmaf(sv.x, w1.y, bv.y), 0.f);
    float a2 = dd * fmaxf(fmaf(sv.x, w1.z, bv.z), 0.f);
    float a3 = dd * fmaxf(fmaf(sv.x, w1.w, bv.w), 0.f);
    int e0 = row_ptr[node], e1 = row_ptr[node + 1];
    int e = e0;
    for (; e + 8 <= e1; e += 8) {
        int s0 = csr[e],     s1 = csr[e + 1], s2 = csr[e + 2], s3 = csr[e + 3];
        int s4 = csr[e + 4], s5 = csr[e + 5], s6 = csr[e + 6], s7 = csr[e + 7];
        float2 v0 = td2[s0], v1 = td2[s1], v2 = td2[s2], v3 = td2[s3];
        float2 v4 = td2[s4], v5 = td2[s5], v6 = td2[s6], v7 = td2[s7];
        a0 += ((v0.y * fmaxf(fmaf(v0.x, w1.x, bv.x), 0.f)
              + v1.y * fmaxf(fmaf(v1.x, w1.x, bv.x), 0.f))
             + (v2.y * fmaxf(fmaf(v2.x, w1.x, bv.x), 0.f)
              + v3.y * fmaxf(fmaf(v3.x, w1.x, bv.x), 0.f)))
            + ((v4.y * fmaxf(fmaf(v4.x, w1.x, bv.x), 0.f)
              + v5.y * fmaxf(fmaf(v5.x, w1.x, bv.x), 0.f))
             + (v6.y * fmaxf(fmaf(v6.x, w1.x, bv.x), 0.f)
              + v7.y * fmaxf(fmaf(v7.x, w1.x, bv.x), 0.f)));
        a1 += ((v0.y * fmaxf(fmaf(v0.x, w1.y, bv.y), 0.f)
              + v1.y * fmaxf(fmaf(v1.x, w1.y, bv.y), 0.f))
             + (v2.y * fmaxf(fmaf(v2.x, w1.y, bv.y), 0.f)
              + v3.y * fmaxf(fmaf(v3.x, w1.y, bv.y), 0.f)))
            + ((v4.y * fmaxf(fmaf(v4.x, w1.y, bv.y), 0.f)
              + v5.y * fmaxf(fmaf(v5.x, w1.y, bv.y), 0.f))
             + (v6.y * fmaxf(fmaf(v6.x, w1.y, bv.y), 0.f)
              + v7.y * fmaxf(fmaf(v7.x, w1.y, bv.y), 0.f)));
        a2 += ((v0.y * fmaxf(fmaf(v0.x, w1.z, bv.z), 0.f)
              + v1.y * fmaxf(fmaf(v1.x, w1.z, bv.z), 0.f))
             + (v2.y * fmaxf(fmaf(v2.x, w1.z, bv.z), 0.f)
              + v3.y * fmaxf(fmaf(v3.x, w1.z, bv.z), 0.f)))
            + ((v4.y * fmaxf(fmaf(v4.x, w1.z, bv.z), 0.f)
              + v5.y * fmaxf(fmaf(v5.x, w1.z, bv.z), 0.f))
             + (v6.y * fmaxf(fmaf(v6.x, w1.z, bv.z), 0.f)
              + v7.y * fmaxf(fmaf(v7.x, w1.z, bv.z), 0.f)));
        a3 += ((v0.y * fmaxf(fmaf(v0.x, w1.w, bv.w), 0.f)
              + v1.y * fmaxf(fmaf(v1.x, w1.w, bv.w), 0.f))
             + (v2.y * fmaxf(fmaf(v2.x, w1.w, bv.w), 0.f)
              + v3.y * fmaxf(fmaf(v3.x, w1.w, bv.w), 0.f)))
            + ((v4.y * fmaxf(fmaf(v4.x, w1.w, bv.w), 0.f)
              + v5.y * fmaxf(fmaf(v5.x, w1.w, bv.w), 0.f))
             + (v6.y * fmaxf(fmaf(v6.x, w1.w, bv.w), 0.f)
              + v7.y * fmaxf(fmaf(v7.x, w1.w, bv.w), 0.f)));
    }
    for (; e < e1; ++e) {
        float2 v = td2[csr[e]];
        a0 += v.y * fmaxf(fmaf(v.x, w1.x, bv.x), 0.f);
        a1 += v.y * fmaxf(fmaf(v.x, w1.y, bv.y), 0.f);
        a2 += v.y * fmaxf(fmaf(v.x, w1.z, bv.z), 0.f);
        a3 += v.y * fmaxf(fmaf(v.x, w1.w, bv.w), 0.f);
    }
    out4[(size_t)node * 32 + lane] = make_float4(a0 * dd, a1 * dd, a2 * dd, a3 * dd);
}

// Half-row aggregation (F-split): out[d][half] = dis[d]*(sum hp[s][half] + hp[d][half])
__global__ void k_agg128h(const float4* __restrict__ hp4, const float* __restrict__ dis,
                          const int* __restrict__ row_ptr, const int* __restrict__ csr,
                          float4* __restrict__ out4, int N, int half) {
    int node = blockIdx.x * 16 + (threadIdx.x >> 4);
    int lane = threadIdx.x & 15;
    if (node >= N) return;
    const int co = half * 16 + lane;           // column offset in float4 units
    float4 self = hp4[(size_t)node * 32 + co];
    float a0 = self.x, a1 = self.y, a2 = self.z, a3 = self.w;
    int e0 = row_ptr[node], e1 = row_ptr[node + 1];
    int e = e0;
    for (; e + 8 <= e1; e += 8) {
        int s0 = csr[e],     s1 = csr[e + 1], s2 = csr[e + 2], s3 = csr[e + 3];
        int s4 = csr[e + 4], s5 = csr[e + 5], s6 = csr[e + 6], s7 = csr[e + 7];
        float4 v0 = hp4[(size_t)s0 * 32 + co];
        float4 v1 = hp4[(size_t)s1 * 32 + co];
        float4 v2 = hp4[(size_t)s2 * 32 + co];
        float4 v3 = hp4[(size_t)s3 * 32 + co];
        float4 v4 = hp4[(size_t)s4 * 32 + co];
        float4 v5 = hp4[(size_t)s5 * 32 + co];
        float4 v6 = hp4[(size_t)s6 * 32 + co];
        float4 v7 = hp4[(size_t)s7 * 32 + co];
        a0 += ((v0.x + v1.x) + (v2.x + v3.x)) + ((v4.x + v5.x) + (v6.x + v7.x));
        a1 += ((v0.y + v1.y) + (v2.y + v3.y)) + ((v4.y + v5.y) + (v6.y + v7.y));
        a2 += ((v0.z + v1.z) + (v2.z + v3.z)) + ((v4.z + v5.z) + (v6.z + v7.z));
        a3 += ((v0.w + v1.w) + (v2.w + v3.w)) + ((v4.w + v5.w) + (v6.w + v7.w));
    }
    for (; e < e1; ++e) {
        int s = csr[e];
        float4 v = hp4[(size_t)s * 32 + co];
        a0 += v.x; a1 += v.y; a2 += v.z; a3 += v.w;
    }
    float d = dis[node];
    f32x4 r = {a0 * d, a1 * d, a2 * d, a3 * d};
    __builtin_nontemporal_store(r, (f32x4*)&out4[(size_t)node * 32 + co]);
}

// ---------------------------------------------------------------------------
// W prep + workspace zeroing, one dispatch (launched first in the stream):
// splits W2/W3 into hi/lo bf16 packed Wp[k>>3][col][k&7], zeroes deg and g.
__global__ void k_wpack2z(const float* __restrict__ W2, const float* __restrict__ W3,
                          unsigned short* __restrict__ Wp2H, unsigned short* __restrict__ Wp2L,
                          unsigned short* __restrict__ Wp3H, unsigned short* __restrict__ Wp3L,
                          int* __restrict__ deg, unsigned int* __restrict__ g, int N) {
    int idx = blockIdx.x * 256 + threadIdx.x;
    if (idx < N) deg[idx] = 0;
    if (idx < N_GRAPHS * 256) g[idx] = 0;
    const float* W; unsigned short *WpH, *WpL; int F, j;
    if (idx < 128 * 128) { W = W2; WpH = Wp2H; WpL = Wp2L; F = 128; j = idx; }
    else if (idx < 128 * 128 + 128 * 256) {
        W = W3; WpH = Wp3H; WpL = Wp3L; F = 256; j = idx - 128 * 128;
    } else return;
    int k = j / F, col = j - k * F;
    float v = W[j];
    unsigned short h = f2bf(v);
    unsigned short l = f2bf(v - bf2f(h));
    int o = ((k >> 3) * F + col) * 8 + (k & 7);
    WpH[o] = h; WpL[o] = l;
}

// MFMA GEMM (split-bf16, 4-term => fp32-level accuracy).
template<int FOUT, bool SCALE, bool FUSE_MAX>
__global__ __launch_bounds__(256, 3) void k_gemm_mfma(
        const float* __restrict__ A,
        const unsigned short* __restrict__ WpH, const unsigned short* __restrict__ WpL,
        const float* __restrict__ b, const float* __restrict__ dis,
        float* __restrict__ outp, const int* __restrict__ batch,
        unsigned int* __restrict__ gmax, int N) {
    __shared__ __align__(16) unsigned short ApH[4 * 4 * 16 * 8];  // [nt][kg][row][e]
    __shared__ __align__(16) unsigned short ApL[4 * 4 * 16 * 8];
    __shared__ __align__(16) unsigned short WlH[4 * 128 * 8];     // [kg][col][e]
    __shared__ __align__(16) unsigned short WlL[4 * 128 * 8];
    const int tid  = threadIdx.x;
    const int lane = tid & 63;
    const int w    = tid >> 6;        // wave id == node-tile nt
    const int n0   = blockIdx.x * 64;
    const int jh   = blockIdx.y;

    f32x4 acc[8];
#pragma unroll
    for (int ct = 0; ct < 8; ++ct) acc[ct] = (f32x4){0.f, 0.f, 0.f, 0.f};

    for (int kc = 0; kc < 128; kc += 32) {
        // ---- stage W (packed, linear copy) ----
#pragma unroll
        for (int it = 0; it < 2; ++it) {
            int q = tid + it * 256;                    // [0,512) f4 units
            int kg = q >> 7, cq = q & 127;
            int src = ((kc >> 3) + kg) * FOUT + jh * 128 + cq;
            ((f32x4*)WlH)[q] = ((const f32x4*)WpH)[src];
            ((f32x4*)WlL)[q] = ((const f32x4*)WpL)[src];
        }
        // ---- stage A (fp32 -> split bf16, packed) ----
#pragma unroll
        for (int it = 0; it < 2; ++it) {
            int idx = tid + it * 256;                  // [0,512)
            int node = idx >> 3, k4 = idx & 7;
            int gn = n0 + node;
            float4 a = (gn < N)
                ? *reinterpret_cast<const float4*>(A + (size_t)gn * 128 + kc + k4 * 4)
                : make_float4(0.f, 0.f, 0.f, 0.f);
            unsigned short h0 = f2bf(a.x), h1 = f2bf(a.y), h2 = f2bf(a.z), h3 = f2bf(a.w);
            unsigned short l0 = f2bf(a.x - bf2f(h0)), l1 = f2bf(a.y - bf2f(h1));
            unsigned short l2 = f2bf(a.z - bf2f(h2)), l3 = f2bf(a.w - bf2f(h3));
            int kg = k4 >> 1, e0 = (k4 & 1) * 4;
            int base = (((node >> 4) * 4 + kg) * 16 + (node & 15)) * 8 + e0;
            *reinterpret_cast<ushort4*>(&ApH[base]) = make_ushort4(h0, h1, h2, h3);
            *reinterpret_cast<ushort4*>(&ApL[base]) = make_ushort4(l0, l1, l2, l3);
        }
        __syncthreads();

        // ---- MFMA ----
        int aidx = (w * 4 + (lane >> 4)) * 16 + (lane & 15);
        bf16x8 aH = ((const bf16x8*)ApH)[aidx];
        bf16x8 aL = ((const bf16x8*)ApL)[aidx];
#pragma unroll
        for (int ct = 0; ct < 8; ++ct) {
            int bidx = (lane >> 4) * 128 + ct * 16 + (lane & 15);
            bf16x8 bH = ((const bf16x8*)WlH)[bidx];
            bf16x8 bL = ((const bf16x8*)WlL)[bidx];
            acc[ct] = __builtin_amdgcn_mfma_f32_16x16x32_bf16(aL, bL, acc[ct], 0, 0, 0);
            acc[ct] = __builtin_amdgcn_mfma_f32_16x16x32_bf16(aL, bH, acc[ct], 0, 0, 0);
            acc[ct] = __builtin_amdgcn_mfma_f32_16x16x32_bf16(aH, bL, acc[ct], 0, 0, 0);
            acc[ct] = __builtin_amdgcn_mfma_f32_16x16x32_bf16(aH, bH, acc[ct], 0, 0, 0);
        }
        __syncthreads();
    }

    // ---- epilogue: C/D layout col=lane&15, row=(lane>>4)*4+reg ----
    const int cl = lane & 15;
    const int r0 = (lane >> 4) * 4;
    float bb[8];
#pragma unroll
    for (int ct = 0; ct < 8; ++ct) bb[ct] = b[jh * 128 + ct * 16 + cl];

    if (!FUSE_MAX) {
#pragma unroll
        for (int r = 0; r < 4; ++r) {
            int node = n0 + w * 16 + r0 + r;
            if (node < N) {
                float dsc = SCALE ? dis[node] : 1.f;
                float* op = outp + (size_t)node * FOUT + jh * 128 + cl;
#pragma unroll
                for (int ct = 0; ct < 8; ++ct) {
                    float v = fmaxf(acc[ct][r] + bb[ct], 0.f);
                    op[ct * 16] = SCALE ? v * dsc : v;
                }
            }
        }
    } else {
        int nbm[4];
#pragma unroll
        for (int r = 0; r < 4; ++r) {
            int node = n0 + w * 16 + r0 + r;
            nbm[r] = (node < N) ? batch[node] : -1;
        }
        int gfirst = batch[n0];
        int glast  = batch[min(n0 + 63, N - 1)];
        for (int gb = gfirst; gb <= glast; ++gb) {
#pragma unroll
            for (int ct = 0; ct < 8; ++ct) {
                float m = 0.f;
#pragma unroll
                for (int r = 0; r < 4; ++r) {
                    float v = fmaxf(acc[ct][r] + bb[ct], 0.f);
                    if (nbm[r] == gb) m = fmaxf(m, v);
                }
                m = fmaxf(m, __shfl_xor(m, 16));
                m = fmaxf(m, __shfl_xor(m, 32));
                if ((lane >> 4) == 0)
                    atomicMax(&gmax[gb * 256 + jh * 128 + ct * 16 + cl],
                              __float_as_uint(m));
            }
        }
    }
}

// final MLP: out = relu( relu(g@Wf1+bf1) @ Wf2 + bf2 )
__global__ void k_mlp(const float* __restrict__ g, const float* __restrict__ Wf1,
                      const float* __restrict__ bf1, const float* __restrict__ Wf2,
                      const float* __restrict__ bf2, float* __restrict__ out) {
    __shared__ float gr[256];
    __shared__ float g1s[128];
    const int gid = blockIdx.x;
    const int tid = threadIdx.x;
    gr[tid] = g[gid * 256 + tid];
    gr[tid + 128] = g[gid * 256 + 128 + tid];
    __syncthreads();
    float acc = bf1[tid];
    for (int k = 0; k < 256; ++k)
        acc = fmaf(gr[k], Wf1[k * 128 + tid], acc);
    g1s[tid] = fmaxf(acc, 0.f);
    __syncthreads();
    if (tid < 10) {
        float a = bf2[tid];
        for (int k = 0; k < 128; ++k)
            a = fmaf(g1s[k], Wf2[k * 10 + tid], a);
        out[gid * 10 + tid] = fmaxf(a, 0.f);
    }
}

// ---------------------------------------------------------------------------
extern "C" void kernel_launch(void* const* d_in, const int* in_sizes, int n_in,
                              void* d_out, int out_size, void* d_ws, size_t ws_size,
                              hipStream_t stream) {
    const float* x   = (const float*)d_in[0];
    const int*   ei  = (const int*)d_in[1];
    const int*   bat = (const int*)d_in[2];
    const float* W1  = (const float*)d_in[3];
    const float* b1  = (const float*)d_in[4];
    const float* W2  = (const float*)d_in[5];
    const float* b2  = (const float*)d_in[6];
    const float* W3  = (const float*)d_in[7];
    const float* b3  = (const float*)d_in[8];
    const float* Wf1 = (const float*)d_in[9];
    const float* bf1 = (const float*)d_in[10];
    const float* Wf2 = (const float*)d_in[11];
    const float* bf2 = (const float*)d_in[12];
    float* out = (float*)d_out;

    const int N = in_sizes[0];          // 50000
    const int E = in_sizes[1] / 2;      // 800000
    const int* src = ei;
    const int* dst = ei + E;

    char* base = (char*)d_ws;
    size_t off = 0;
    auto carve = [&](size_t bytes) -> char* {
        char* p = base + off;
        off = (off + bytes + 255) & ~(size_t)255;
        return p;
    };
    const int nb = (N + 255) / 256;
    int*    deg     = (int*)   carve((size_t)N * 4);
    int*    fill    = (int*)   carve((size_t)N * 4);
    int*    row_ptr = (int*)   carve((size_t)(N + 1) * 4);
    int*    csr     = (int*)   carve((size_t)E * 4);
    float*  dis     = (float*) carve((size_t)N * 4);
    float*  xp      = (float*) carve((size_t)N * 4);
    float2* td2     = (float2*)carve((size_t)N * 8);
    float*  A2      = (float*) carve((size_t)N * 128 * 4);
    float*  B2      = (float*) carve((size_t)N * 128 * 4);
    float*  A3      = (float*) carve((size_t)N * 128 * 4);
    unsigned int* g = (unsigned int*)carve((size_t)N_GRAPHS * 256 * 4);
    int*    bsum    = (int*)   carve((size_t)nb * 4);
    int*    boff    = (int*)   carve((size_t)nb * 4);
    unsigned short* Wp2H = (unsigned short*)carve((size_t)128 * 128 * 2);
    unsigned short* Wp2L = (unsigned short*)carve((size_t)128 * 128 * 2);
    unsigned short* Wp3H = (unsigned short*)carve((size_t)128 * 256 * 2);
    unsigned short* Wp3L = (unsigned short*)carve((size_t)128 * 256 * 2);
    (void)ws_size; (void)n_in; (void)out_size;

    int eb = (E + 255) / 256;

    // W split+pack + zero deg/g (one dispatch, replaces both memsets)
    k_wpack2z<<<nb, 256, 0, stream>>>(W2, W3, Wp2H, Wp2L, Wp3H, Wp3L, deg, g, N);

    k_deg<<<eb, 256, 0, stream>>>(dst, E, deg);
    k_dis_bsum<<<nb, 256, 0, stream>>>(deg, x, dis, xp, bsum, N);
    k_scan_sums<<<1, 256, 0, stream>>>(bsum, nb, boff);
    k_scan_apply<<<nb, 256, 0, stream>>>(deg, boff, row_ptr, fill, N);
    k_scatter<<<eb, 256, 0, stream>>>(src, dst, E, fill, csr);

    k_agg_scalar<<<nb, 256, 0, stream>>>(xp, dis, row_ptr, csr, td2, N);

    const int gx = (N + 63) / 64;
    const int ab = (N + 7) / 8;
    const int ab16 = (N + 15) / 16;

    // layer 1+2: recompute-gather h1 -> A2 (LDS-free), then MFMA GEMM W2 -> B2
    k_h1agg<<<ab, 256, 0, stream>>>(td2, (const float4*)W1, (const float4*)b1,
                                    row_ptr, csr, (float4*)A2, N);
    k_gemm_mfma<128, true, false><<<dim3(gx, 1), 256, 0, stream>>>(
        A2, Wp2H, Wp2L, b2, dis, B2, nullptr, nullptr, N);

    // layer 3: F-split row-gather aggregation (two 12.8MB slabs), then
    // MFMA GEMM W3 + fused max-pool
    k_agg128h<<<ab16, 256, 0, stream>>>((const float4*)B2, dis, row_ptr, csr,
                                        (float4*)A3, N, 0);
    k_agg128h<<<ab16, 256, 0, stream>>>((const float4*)B2, dis, row_ptr, csr,
                                        (float4*)A3, N, 1);
    k_gemm_mfma<256, false, true><<<dim3(gx, 2), 256, 0, stream>>>(
        A3, Wp3H, Wp3L, b3, nullptr, nullptr, bat, g, N);

    k_mlp<<<N_GRAPHS, 128, 0, stream>>>((const float*)g, Wf1, bf1, Wf2, bf2, out);
}

// Round 14
// 211.051 us; speedup vs baseline: 1.2026x; 1.2026x over previous
//
#include <hip/hip_runtime.h>
#include <hip/hip_bf16.h>

#define N_GRAPHS 64

typedef float f32x4 __attribute__((ext_vector_type(4)));
typedef short bf16x8 __attribute__((ext_vector_type(8)));

__device__ inline unsigned short f2bf(float f) {   // fp32 -> bf16 RNE
    unsigned int u = __float_as_uint(f);
    u = u + 0x7fffu + ((u >> 16) & 1u);
    return (unsigned short)(u >> 16);
}
__device__ inline float bf2f(unsigned short h) {
    return __uint_as_float(((unsigned int)h) << 16);
}

// ---------------------------------------------------------------------------
// deg count + per-edge slot assignment in ONE atomic pass:
// pos[e] = slot of edge e within its destination row (coalesced write).
__global__ void k_degpos(const int* __restrict__ dst, int E,
                         int* __restrict__ deg, int* __restrict__ pos) {
    int e = blockIdx.x * blockDim.x + threadIdx.x;
    if (e < E) pos[e] = atomicAdd(&deg[dst[e]], 1);
}

// place edges: no atomics — row_ptr gather (L2-resident 200KB) + random store
__global__ void k_place(const int* __restrict__ src, const int* __restrict__ dst,
                        const int* __restrict__ pos, const int* __restrict__ row_ptr,
                        int E, int* __restrict__ csr) {
    int e = blockIdx.x * blockDim.x + threadIdx.x;
    if (e < E) csr[row_ptr[dst[e]] + pos[e]] = src[e];
}

__global__ void k_dis_bsum(const int* __restrict__ deg, const float* __restrict__ x,
                           float* __restrict__ dis, float* __restrict__ xp,
                           int* __restrict__ bsum, int N) {
    int i = blockIdx.x * 256 + threadIdx.x;
    int dv = (i < N) ? deg[i] : 0;
    if (i < N) {
        float d = rsqrtf((float)(dv + 1));
        dis[i] = d;
        xp[i]  = d * x[i];
    }
    int v = dv;
#pragma unroll
    for (int o = 1; o < 64; o <<= 1) v += __shfl_xor(v, o);
    __shared__ int ws4[4];
    if ((threadIdx.x & 63) == 0) ws4[threadIdx.x >> 6] = v;
    __syncthreads();
    if (threadIdx.x == 0) bsum[blockIdx.x] = ws4[0] + ws4[1] + ws4[2] + ws4[3];
}

__device__ inline int block_scan_inc(int v, int* wsum) {
    int lane = threadIdx.x & 63, w = threadIdx.x >> 6;
    int iv = v;
#pragma unroll
    for (int o = 1; o < 64; o <<= 1) {
        int t = __shfl_up(iv, o);
        if (lane >= o) iv += t;
    }
    if (lane == 63) wsum[w] = iv;
    __syncthreads();
    int add = 0;
    for (int k = 0; k < w; ++k) add += wsum[k];
    return iv + add;
}

__global__ void k_scan_sums(const int* __restrict__ bsum, int nb, int* __restrict__ boff) {
    __shared__ int wsum[4];
    int tid = threadIdx.x;
    int v = (tid < nb) ? bsum[tid] : 0;
    int inc = block_scan_inc(v, wsum);
    if (tid < nb) boff[tid] = inc - v;
}

__global__ void k_scan_apply(const int* __restrict__ deg, const int* __restrict__ boff,
                             int* __restrict__ row_ptr, int N) {
    __shared__ int wsum[4];
    int b = blockIdx.x, i = b * 256 + threadIdx.x;
    int v = (i < N) ? deg[i] : 0;
    int inc = block_scan_inc(v, wsum) + boff[b];
    if (i < N) {
        row_ptr[i] = inc - v;
        if (i == N - 1) row_ptr[N] = inc;
    }
}

// td2[d] = ( dis[d] * (sum xp[s] + xp[d]),  dis[d] )
__global__ void k_agg_scalar(const float* __restrict__ xp, const float* __restrict__ dis,
                             const int* __restrict__ row_ptr, const int* __restrict__ csr,
                             float2* __restrict__ td2, int N) {
    int d = blockIdx.x * blockDim.x + threadIdx.x;
    if (d >= N) return;
    float acc = xp[d];
    int e0 = row_ptr[d], e1 = row_ptr[d + 1];
    int e = e0;
    for (; e + 8 <= e1; e += 8) {
        int s0 = csr[e],     s1 = csr[e + 1], s2 = csr[e + 2], s3 = csr[e + 3];
        int s4 = csr[e + 4], s5 = csr[e + 5], s6 = csr[e + 6], s7 = csr[e + 7];
        acc += ((xp[s0] + xp[s1]) + (xp[s2] + xp[s3]))
             + ((xp[s4] + xp[s5]) + (xp[s6] + xp[s7]));
    }
    for (; e < e1; ++e) acc += xp[csr[e]];
    float dd = dis[d];
    td2[d] = make_float2(dd * acc, dd);
}

// ---------------------------------------------------------------------------
// Layer-2 aggregation with rank-1 h1 recompute (LDS-free, high occupancy)
__global__ void k_h1agg(const float2* __restrict__ td2,
                        const float4* __restrict__ W1f4, const float4* __restrict__ b1f4,
                        const int* __restrict__ row_ptr, const int* __restrict__ csr,
                        float4* __restrict__ out4, int N) {
    int node = blockIdx.x * 8 + (threadIdx.x >> 5);
    int lane = threadIdx.x & 31;
    if (node >= N) return;
    const float4 w1 = W1f4[lane];
    const float4 bv = b1f4[lane];
    float2 sv = td2[node];
    float dd = sv.y;
    float a0 = dd * fmaxf(fmaf(sv.x, w1.x, bv.x), 0.f);
    float a1 = dd * fmaxf(fmaf(sv.x, w1.y, bv.y), 0.f);
    float a2 = dd * fmaxf(fmaf(sv.x, w1.z, bv.z), 0.f);
    float a3 = dd * fmaxf(fmaf(sv.x, w1.w, bv.w), 0.f);
    int e0 = row_ptr[node], e1 = row_ptr[node + 1];
    int e = e0;
    for (; e + 8 <= e1; e += 8) {
        int s0 = csr[e],     s1 = csr[e + 1], s2 = csr[e + 2], s3 = csr[e + 3];
        int s4 = csr[e + 4], s5 = csr[e + 5], s6 = csr[e + 6], s7 = csr[e + 7];
        float2 v0 = td2[s0], v1 = td2[s1], v2 = td2[s2], v3 = td2[s3];
        float2 v4 = td2[s4], v5 = td2[s5], v6 = td2[s6], v7 = td2[s7];
        a0 += ((v0.y * fmaxf(fmaf(v0.x, w1.x, bv.x), 0.f)
              + v1.y * fmaxf(fmaf(v1.x, w1.x, bv.x), 0.f))
             + (v2.y * fmaxf(fmaf(v2.x, w1.x, bv.x), 0.f)
              + v3.y * fmaxf(fmaf(v3.x, w1.x, bv.x), 0.f)))
            + ((v4.y * fmaxf(fmaf(v4.x, w1.x, bv.x), 0.f)
              + v5.y * fmaxf(fmaf(v5.x, w1.x, bv.x), 0.f))
             + (v6.y * fmaxf(fmaf(v6.x, w1.x, bv.x), 0.f)
              + v7.y * fmaxf(fmaf(v7.x, w1.x, bv.x), 0.f)));
        a1 += ((v0.y * fmaxf(fmaf(v0.x, w1.y, bv.y), 0.f)
              + v1.y * fmaxf(fmaf(v1.x, w1.y, bv.y), 0.f))
             + (v2.y * fmaxf(fmaf(v2.x, w1.y, bv.y), 0.f)
              + v3.y * fmaxf(fmaf(v3.x, w1.y, bv.y), 0.f)))
            + ((v4.y * fmaxf(fmaf(v4.x, w1.y, bv.y), 0.f)
              + v5.y * fmaxf(fmaf(v5.x, w1.y, bv.y), 0.f))
             + (v6.y * fmaxf(fmaf(v6.x, w1.y, bv.y), 0.f)
              + v7.y * fmaxf(fmaf(v7.x, w1.y, bv.y), 0.f)));
        a2 += ((v0.y * fmaxf(fmaf(v0.x, w1.z, bv.z), 0.f)
              + v1.y * fmaxf(fmaf(v1.x, w1.z, bv.z), 0.f))
             + (v2.y * fmaxf(fmaf(v2.x, w1.z, bv.z), 0.f)
              + v3.y * fmaxf(fmaf(v3.x, w1.z, bv.z), 0.f)))
            + ((v4.y * fmaxf(fmaf(v4.x, w1.z, bv.z), 0.f)
              + v5.y * fmaxf(fmaf(v5.x, w1.z, bv.z), 0.f))
             + (v6.y * fmaxf(fmaf(v6.x, w1.z, bv.z), 0.f)
              + v7.y * fmaxf(fmaf(v7.x, w1.z, bv.z), 0.f)));
        a3 += ((v0.y * fmaxf(fmaf(v0.x, w1.w, bv.w), 0.f)
              + v1.y * fmaxf(fmaf(v1.x, w1.w, bv.w), 0.f))
             + (v2.y * fmaxf(fmaf(v2.x, w1.w, bv.w), 0.f)
              + v3.y * fmaxf(fmaf(v3.x, w1.w, bv.w), 0.f)))
            + ((v4.y * fmaxf(fmaf(v4.x, w1.w, bv.w), 0.f)
              + v5.y * fmaxf(fmaf(v5.x, w1.w, bv.w), 0.f))
             + (v6.y * fmaxf(fmaf(v6.x, w1.w, bv.w), 0.f)
              + v7.y * fmaxf(fmaf(v7.x, w1.w, bv.w), 0.f)));
    }
    for (; e < e1; ++e) {
        float2 v = td2[csr[e]];
        a0 += v.y * fmaxf(fmaf(v.x, w1.x, bv.x), 0.f);
        a1 += v.y * fmaxf(fmaf(v.x, w1.y, bv.y), 0.f);
        a2 += v.y * fmaxf(fmaf(v.x, w1.z, bv.z), 0.f);
        a3 += v.y * fmaxf(fmaf(v.x, w1.w, bv.w), 0.f);
    }
    out4[(size_t)node * 32 + lane] = make_float4(a0 * dd, a1 * dd, a2 * dd, a3 * dd);
}

// Half-row aggregation (F-split): out[d][half] = dis[d]*(sum hp[s][half] + hp[d][half])
__global__ void k_agg128h(const float4* __restrict__ hp4, const float* __restrict__ dis,
                          const int* __restrict__ row_ptr, const int* __restrict__ csr,
                          float4* __restrict__ out4, int N, int half) {
    int node = blockIdx.x * 16 + (threadIdx.x >> 4);
    int lane = threadIdx.x & 15;
    if (node >= N) return;
    const int co = half * 16 + lane;           // column offset in float4 units
    float4 self = hp4[(size_t)node * 32 + co];
    float a0 = self.x, a1 = self.y, a2 = self.z, a3 = self.w;
    int e0 = row_ptr[node], e1 = row_ptr[node + 1];
    int e = e0;
    for (; e + 8 <= e1; e += 8) {
        int s0 = csr[e],     s1 = csr[e + 1], s2 = csr[e + 2], s3 = csr[e + 3];
        int s4 = csr[e + 4], s5 = csr[e + 5], s6 = csr[e + 6], s7 = csr[e + 7];
        float4 v0 = hp4[(size_t)s0 * 32 + co];
        float4 v1 = hp4[(size_t)s1 * 32 + co];
        float4 v2 = hp4[(size_t)s2 * 32 + co];
        float4 v3 = hp4[(size_t)s3 * 32 + co];
        float4 v4 = hp4[(size_t)s4 * 32 + co];
        float4 v5 = hp4[(size_t)s5 * 32 + co];
        float4 v6 = hp4[(size_t)s6 * 32 + co];
        float4 v7 = hp4[(size_t)s7 * 32 + co];
        a0 += ((v0.x + v1.x) + (v2.x + v3.x)) + ((v4.x + v5.x) + (v6.x + v7.x));
        a1 += ((v0.y + v1.y) + (v2.y + v3.y)) + ((v4.y + v5.y) + (v6.y + v7.y));
        a2 += ((v0.z + v1.z) + (v2.z + v3.z)) + ((v4.z + v5.z) + (v6.z + v7.z));
        a3 += ((v0.w + v1.w) + (v2.w + v3.w)) + ((v4.w + v5.w) + (v6.w + v7.w));
    }
    for (; e < e1; ++e) {
        int s = csr[e];
        float4 v = hp4[(size_t)s * 32 + co];
        a0 += v.x; a1 += v.y; a2 += v.z; a3 += v.w;
    }
    float d = dis[node];
    f32x4 r = {a0 * d, a1 * d, a2 * d, a3 * d};
    __builtin_nontemporal_store(r, (f32x4*)&out4[(size_t)node * 32 + co]);
}

// ---------------------------------------------------------------------------
// W prep + workspace zeroing, one dispatch (launched first in the stream):
// splits W2/W3 into hi/lo bf16 packed Wp[k>>3][col][k&7], zeroes deg and g.
__global__ void k_wpack2z(const float* __restrict__ W2, const float* __restrict__ W3,
                          unsigned short* __restrict__ Wp2H, unsigned short* __restrict__ Wp2L,
                          unsigned short* __restrict__ Wp3H, unsigned short* __restrict__ Wp3L,
                          int* __restrict__ deg, unsigned int* __restrict__ g, int N) {
    int idx = blockIdx.x * 256 + threadIdx.x;
    if (idx < N) deg[idx] = 0;
    if (idx < N_GRAPHS * 256) g[idx] = 0;
    const float* W; unsigned short *WpH, *WpL; int F, j;
    if (idx < 128 * 128) { W = W2; WpH = Wp2H; WpL = Wp2L; F = 128; j = idx; }
    else if (idx < 128 * 128 + 128 * 256) {
        W = W3; WpH = Wp3H; WpL = Wp3L; F = 256; j = idx - 128 * 128;
    } else return;
    int k = j / F, col = j - k * F;
    float v = W[j];
    unsigned short h = f2bf(v);
    unsigned short l = f2bf(v - bf2f(h));
    int o = ((k >> 3) * F + col) * 8 + (k & 7);
    WpH[o] = h; WpL[o] = l;
}

// MFMA GEMM (split-bf16, 4-term => fp32-level accuracy).
template<int FOUT, bool SCALE, bool FUSE_MAX>
__global__ __launch_bounds__(256, 3) void k_gemm_mfma(
        const float* __restrict__ A,
        const unsigned short* __restrict__ WpH, const unsigned short* __restrict__ WpL,
        const float* __restrict__ b, const float* __restrict__ dis,
        float* __restrict__ outp, const int* __restrict__ batch,
        unsigned int* __restrict__ gmax, int N) {
    __shared__ __align__(16) unsigned short ApH[4 * 4 * 16 * 8];  // [nt][kg][row][e]
    __shared__ __align__(16) unsigned short ApL[4 * 4 * 16 * 8];
    __shared__ __align__(16) unsigned short WlH[4 * 128 * 8];     // [kg][col][e]
    __shared__ __align__(16) unsigned short WlL[4 * 128 * 8];
    const int tid  = threadIdx.x;
    const int lane = tid & 63;
    const int w    = tid >> 6;        // wave id == node-tile nt
    const int n0   = blockIdx.x * 64;
    const int jh   = blockIdx.y;

    f32x4 acc[8];
#pragma unroll
    for (int ct = 0; ct < 8; ++ct) acc[ct] = (f32x4){0.f, 0.f, 0.f, 0.f};

    for (int kc = 0; kc < 128; kc += 32) {
        // ---- stage W (packed, linear copy) ----
#pragma unroll
        for (int it = 0; it < 2; ++it) {
            int q = tid + it * 256;                    // [0,512) f4 units
            int kg = q >> 7, cq = q & 127;
            int src = ((kc >> 3) + kg) * FOUT + jh * 128 + cq;
            ((f32x4*)WlH)[q] = ((const f32x4*)WpH)[src];
            ((f32x4*)WlL)[q] = ((const f32x4*)WpL)[src];
        }
        // ---- stage A (fp32 -> split bf16, packed) ----
#pragma unroll
        for (int it = 0; it < 2; ++it) {
            int idx = tid + it * 256;                  // [0,512)
            int node = idx >> 3, k4 = idx & 7;
            int gn = n0 + node;
            float4 a = (gn < N)
                ? *reinterpret_cast<const float4*>(A + (size_t)gn * 128 + kc + k4 * 4)
                : make_float4(0.f, 0.f, 0.f, 0.f);
            unsigned short h0 = f2bf(a.x), h1 = f2bf(a.y), h2 = f2bf(a.z), h3 = f2bf(a.w);
            unsigned short l0 = f2bf(a.x - bf2f(h0)), l1 = f2bf(a.y - bf2f(h1));
            unsigned short l2 = f2bf(a.z - bf2f(h2)), l3 = f2bf(a.w - bf2f(h3));
            int kg = k4 >> 1, e0 = (k4 & 1) * 4;
            int base = (((node >> 4) * 4 + kg) * 16 + (node & 15)) * 8 + e0;
            *reinterpret_cast<ushort4*>(&ApH[base]) = make_ushort4(h0, h1, h2, h3);
            *reinterpret_cast<ushort4*>(&ApL[base]) = make_ushort4(l0, l1, l2, l3);
        }
        __syncthreads();

        // ---- MFMA ----
        int aidx = (w * 4 + (lane >> 4)) * 16 + (lane & 15);
        bf16x8 aH = ((const bf16x8*)ApH)[aidx];
        bf16x8 aL = ((const bf16x8*)ApL)[aidx];
#pragma unroll
        for (int ct = 0; ct < 8; ++ct) {
            int bidx = (lane >> 4) * 128 + ct * 16 + (lane & 15);
            bf16x8 bH = ((const bf16x8*)WlH)[bidx];
            bf16x8 bL = ((const bf16x8*)WlL)[bidx];
            acc[ct] = __builtin_amdgcn_mfma_f32_16x16x32_bf16(aL, bL, acc[ct], 0, 0, 0);
            acc[ct] = __builtin_amdgcn_mfma_f32_16x16x32_bf16(aL, bH, acc[ct], 0, 0, 0);
            acc[ct] = __builtin_amdgcn_mfma_f32_16x16x32_bf16(aH, bL, acc[ct], 0, 0, 0);
            acc[ct] = __builtin_amdgcn_mfma_f32_16x16x32_bf16(aH, bH, acc[ct], 0, 0, 0);
        }
        __syncthreads();
    }

    // ---- epilogue: C/D layout col=lane&15, row=(lane>>4)*4+reg ----
    const int cl = lane & 15;
    const int r0 = (lane >> 4) * 4;
    float bb[8];
#pragma unroll
    for (int ct = 0; ct < 8; ++ct) bb[ct] = b[jh * 128 + ct * 16 + cl];

    if (!FUSE_MAX) {
#pragma unroll
        for (int r = 0; r < 4; ++r) {
            int node = n0 + w * 16 + r0 + r;
            if (node < N) {
                float dsc = SCALE ? dis[node] : 1.f;
                float* op = outp + (size_t)node * FOUT + jh * 128 + cl;
#pragma unroll
                for (int ct = 0; ct < 8; ++ct) {
                    float v = fmaxf(acc[ct][r] + bb[ct], 0.f);
                    op[ct * 16] = SCALE ? v * dsc : v;
                }
            }
        }
    } else {
        int nbm[4];
#pragma unroll
        for (int r = 0; r < 4; ++r) {
            int node = n0 + w * 16 + r0 + r;
            nbm[r] = (node < N) ? batch[node] : -1;
        }
        int gfirst = batch[n0];
        int glast  = batch[min(n0 + 63, N - 1)];
        for (int gb = gfirst; gb <= glast; ++gb) {
#pragma unroll
            for (int ct = 0; ct < 8; ++ct) {
                float m = 0.f;
#pragma unroll
                for (int r = 0; r < 4; ++r) {
                    float v = fmaxf(acc[ct][r] + bb[ct], 0.f);
                    if (nbm[r] == gb) m = fmaxf(m, v);
                }
                m = fmaxf(m, __shfl_xor(m, 16));
                m = fmaxf(m, __shfl_xor(m, 32));
                if ((lane >> 4) == 0)
                    atomicMax(&gmax[gb * 256 + jh * 128 + ct * 16 + cl],
                              __float_as_uint(m));
            }
        }
    }
}

// final MLP: out = relu( relu(g@Wf1+bf1) @ Wf2 + bf2 )
__global__ void k_mlp(const float* __restrict__ g, const float* __restrict__ Wf1,
                      const float* __restrict__ bf1, const float* __restrict__ Wf2,
                      const float* __restrict__ bf2, float* __restrict__ out) {
    __shared__ float gr[256];
    __shared__ float g1s[128];
    const int gid = blockIdx.x;
    const int tid = threadIdx.x;
    gr[tid] = g[gid * 256 + tid];
    gr[tid + 128] = g[gid * 256 + 128 + tid];
    __syncthreads();
    float acc = bf1[tid];
    for (int k = 0; k < 256; ++k)
        acc = fmaf(gr[k], Wf1[k * 128 + tid], acc);
    g1s[tid] = fmaxf(acc, 0.f);
    __syncthreads();
    if (tid < 10) {
        float a = bf2[tid];
        for (int k = 0; k < 128; ++k)
            a = fmaf(g1s[k], Wf2[k * 10 + tid], a);
        out[gid * 10 + tid] = fmaxf(a, 0.f);
    }
}

// ---------------------------------------------------------------------------
extern "C" void kernel_launch(void* const* d_in, const int* in_sizes, int n_in,
                              void* d_out, int out_size, void* d_ws, size_t ws_size,
                              hipStream_t stream) {
    const float* x   = (const float*)d_in[0];
    const int*   ei  = (const int*)d_in[1];
    const int*   bat = (const int*)d_in[2];
    const float* W1  = (const float*)d_in[3];
    const float* b1  = (const float*)d_in[4];
    const float* W2  = (const float*)d_in[5];
    const float* b2  = (const float*)d_in[6];
    const float* W3  = (const float*)d_in[7];
    const float* b3  = (const float*)d_in[8];
    const float* Wf1 = (const float*)d_in[9];
    const float* bf1 = (const float*)d_in[10];
    const float* Wf2 = (const float*)d_in[11];
    const float* bf2 = (const float*)d_in[12];
    float* out = (float*)d_out;

    const int N = in_sizes[0];          // 50000
    const int E = in_sizes[1] / 2;      // 800000
    const int* src = ei;
    const int* dst = ei + E;

    char* base = (char*)d_ws;
    size_t off = 0;
    auto carve = [&](size_t bytes) -> char* {
        char* p = base + off;
        off = (off + bytes + 255) & ~(size_t)255;
        return p;
    };
    const int nb = (N + 255) / 256;
    int*    deg     = (int*)   carve((size_t)N * 4);
    int*    epos    = (int*)   carve((size_t)E * 4);
    int*    row_ptr = (int*)   carve((size_t)(N + 1) * 4);
    int*    csr     = (int*)   carve((size_t)E * 4);
    float*  dis     = (float*) carve((size_t)N * 4);
    float*  xp      = (float*) carve((size_t)N * 4);
    float2* td2     = (float2*)carve((size_t)N * 8);
    float*  A2      = (float*) carve((size_t)N * 128 * 4);
    float*  B2      = (float*) carve((size_t)N * 128 * 4);
    float*  A3      = (float*) carve((size_t)N * 128 * 4);
    unsigned int* g = (unsigned int*)carve((size_t)N_GRAPHS * 256 * 4);
    int*    bsum    = (int*)   carve((size_t)nb * 4);
    int*    boff    = (int*)   carve((size_t)nb * 4);
    unsigned short* Wp2H = (unsigned short*)carve((size_t)128 * 128 * 2);
    unsigned short* Wp2L = (unsigned short*)carve((size_t)128 * 128 * 2);
    unsigned short* Wp3H = (unsigned short*)carve((size_t)128 * 256 * 2);
    unsigned short* Wp3L = (unsigned short*)carve((size_t)128 * 256 * 2);
    (void)ws_size; (void)n_in; (void)out_size;

    int eb = (E + 255) / 256;

    // W split+pack + zero deg/g (one dispatch, replaces both memsets)
    k_wpack2z<<<nb, 256, 0, stream>>>(W2, W3, Wp2H, Wp2L, Wp3H, Wp3L, deg, g, N);

    // CSR build: ONE atomic pass (deg+pos), scan, then atomic-free placement
    k_degpos<<<eb, 256, 0, stream>>>(dst, E, deg, epos);
    k_dis_bsum<<<nb, 256, 0, stream>>>(deg, x, dis, xp, bsum, N);
    k_scan_sums<<<1, 256, 0, stream>>>(bsum, nb, boff);
    k_scan_apply<<<nb, 256, 0, stream>>>(deg, boff, row_ptr, N);
    k_place<<<eb, 256, 0, stream>>>(src, dst, epos, row_ptr, E, csr);

    k_agg_scalar<<<nb, 256, 0, stream>>>(xp, dis, row_ptr, csr, td2, N);

    const int gx = (N + 63) / 64;
    const int ab = (N + 7) / 8;
    const int ab16 = (N + 15) / 16;

    // layer 1+2: recompute-gather h1 -> A2 (LDS-free), then MFMA GEMM W2 -> B2
    k_h1agg<<<ab, 256, 0, stream>>>(td2, (const float4*)W1, (const float4*)b1,
                                    row_ptr, csr, (float4*)A2, N);
    k_gemm_mfma<128, true, false><<<dim3(gx, 1), 256, 0, stream>>>(
        A2, Wp2H, Wp2L, b2, dis, B2, nullptr, nullptr, N);

    // layer 3: F-split row-gather aggregation (two 12.8MB slabs), then
    // MFMA GEMM W3 + fused max-pool
    k_agg128h<<<ab16, 256, 0, stream>>>((const float4*)B2, dis, row_ptr, csr,
                                        (float4*)A3, N, 0);
    k_agg128h<<<ab16, 256, 0, stream>>>((const float4*)B2, dis, row_ptr, csr,
                                        (float4*)A3, N, 1);
    k_gemm_mfma<256, false, true><<<dim3(gx, 2), 256, 0, stream>>>(
        A3, Wp3H, Wp3L, b3, nullptr, nullptr, bat, g, N);

    k_mlp<<<N_GRAPHS, 128, 0, stream>>>((const float*)g, Wf1, bf1, Wf2, bf2, out);
}

// Round 15
// 207.313 us; speedup vs baseline: 1.2243x; 1.0180x over previous
//
#include <hip/hip_runtime.h>
#include <hip/hip_bf16.h>

#define N_GRAPHS 64

typedef float f32x4 __attribute__((ext_vector_type(4)));
typedef short bf16x8 __attribute__((ext_vector_type(8)));

__device__ inline unsigned short f2bf(float f) {   // fp32 -> bf16 RNE
    unsigned int u = __float_as_uint(f);
    u = u + 0x7fffu + ((u >> 16) & 1u);
    return (unsigned short)(u >> 16);
}
__device__ inline float bf2f(unsigned short h) {
    return __uint_as_float(((unsigned int)h) << 16);
}

// ---------------------------------------------------------------------------
// deg count + per-edge slot assignment in ONE atomic pass (slot as ushort).
__global__ void k_degpos(const int* __restrict__ dst, int E,
                         int* __restrict__ deg, unsigned short* __restrict__ pos) {
    int e = blockIdx.x * blockDim.x + threadIdx.x;
    if (e < E) pos[e] = (unsigned short)atomicAdd(&deg[dst[e]], 1);
}

// place edges: no atomics — row_ptr gather + random 2B store (16-bit CSR)
__global__ void k_place(const int* __restrict__ src, const int* __restrict__ dst,
                        const unsigned short* __restrict__ pos,
                        const int* __restrict__ row_ptr,
                        int E, unsigned short* __restrict__ csr) {
    int e = blockIdx.x * blockDim.x + threadIdx.x;
    if (e < E) csr[row_ptr[dst[e]] + (int)pos[e]] = (unsigned short)src[e];
}

__global__ void k_dis_bsum(const int* __restrict__ deg, const float* __restrict__ x,
                           float* __restrict__ dis, float* __restrict__ xp,
                           int* __restrict__ bsum, int N) {
    int i = blockIdx.x * 256 + threadIdx.x;
    int dv = (i < N) ? deg[i] : 0;
    if (i < N) {
        float d = rsqrtf((float)(dv + 1));
        dis[i] = d;
        xp[i]  = d * x[i];
    }
    int v = dv;
#pragma unroll
    for (int o = 1; o < 64; o <<= 1) v += __shfl_xor(v, o);
    __shared__ int ws4[4];
    if ((threadIdx.x & 63) == 0) ws4[threadIdx.x >> 6] = v;
    __syncthreads();
    if (threadIdx.x == 0) bsum[blockIdx.x] = ws4[0] + ws4[1] + ws4[2] + ws4[3];
}

__device__ inline int block_scan_inc(int v, int* wsum) {
    int lane = threadIdx.x & 63, w = threadIdx.x >> 6;
    int iv = v;
#pragma unroll
    for (int o = 1; o < 64; o <<= 1) {
        int t = __shfl_up(iv, o);
        if (lane >= o) iv += t;
    }
    if (lane == 63) wsum[w] = iv;
    __syncthreads();
    int add = 0;
    for (int k = 0; k < w; ++k) add += wsum[k];
    return iv + add;
}

__global__ void k_scan_sums(const int* __restrict__ bsum, int nb, int* __restrict__ boff) {
    __shared__ int wsum[4];
    int tid = threadIdx.x;
    int v = (tid < nb) ? bsum[tid] : 0;
    int inc = block_scan_inc(v, wsum);
    if (tid < nb) boff[tid] = inc - v;
}

__global__ void k_scan_apply(const int* __restrict__ deg, const int* __restrict__ boff,
                             int* __restrict__ row_ptr, int N) {
    __shared__ int wsum[4];
    int b = blockIdx.x, i = b * 256 + threadIdx.x;
    int v = (i < N) ? deg[i] : 0;
    int inc = block_scan_inc(v, wsum) + boff[b];
    if (i < N) {
        row_ptr[i] = inc - v;
        if (i == N - 1) row_ptr[N] = inc;
    }
}

// td2[d] = ( dis[d] * (sum xp[s] + xp[d]),  dis[d] )
__global__ void k_agg_scalar(const float* __restrict__ xp, const float* __restrict__ dis,
                             const int* __restrict__ row_ptr,
                             const unsigned short* __restrict__ csr,
                             float2* __restrict__ td2, int N) {
    int d = blockIdx.x * blockDim.x + threadIdx.x;
    if (d >= N) return;
    float acc = xp[d];
    int e0 = row_ptr[d], e1 = row_ptr[d + 1];
    int e = e0;
    for (; e + 8 <= e1; e += 8) {
        int s0 = csr[e],     s1 = csr[e + 1], s2 = csr[e + 2], s3 = csr[e + 3];
        int s4 = csr[e + 4], s5 = csr[e + 5], s6 = csr[e + 6], s7 = csr[e + 7];
        acc += ((xp[s0] + xp[s1]) + (xp[s2] + xp[s3]))
             + ((xp[s4] + xp[s5]) + (xp[s6] + xp[s7]));
    }
    for (; e < e1; ++e) acc += xp[csr[e]];
    float dd = dis[d];
    td2[d] = make_float2(dd * acc, dd);
}

// ---------------------------------------------------------------------------
// Layer-2 aggregation with rank-1 h1 recompute (LDS-free, high occupancy)
__global__ void k_h1agg(const float2* __restrict__ td2,
                        const float4* __restrict__ W1f4, const float4* __restrict__ b1f4,
                        const int* __restrict__ row_ptr,
                        const unsigned short* __restrict__ csr,
                        float4* __restrict__ out4, int N) {
    int node = blockIdx.x * 8 + (threadIdx.x >> 5);
    int lane = threadIdx.x & 31;
    if (node >= N) return;
    const float4 w1 = W1f4[lane];
    const float4 bv = b1f4[lane];
    float2 sv = td2[node];
    float dd = sv.y;
    float a0 = dd * fmaxf(fmaf(sv.x, w1.x, bv.x), 0.f);
    float a1 = dd * fmaxf(fmaf(sv.x, w1.y, bv.y), 0.f);
    float a2 = dd * fmaxf(fmaf(sv.x, w1.z, bv.z), 0.f);
    float a3 = dd * fmaxf(fmaf(sv.x, w1.w, bv.w), 0.f);
    int e0 = row_ptr[node], e1 = row_ptr[node + 1];
    int e = e0;
    for (; e + 8 <= e1; e += 8) {
        int s0 = csr[e],     s1 = csr[e + 1], s2 = csr[e + 2], s3 = csr[e + 3];
        int s4 = csr[e + 4], s5 = csr[e + 5], s6 = csr[e + 6], s7 = csr[e + 7];
        float2 v0 = td2[s0], v1 = td2[s1], v2 = td2[s2], v3 = td2[s3];
        float2 v4 = td2[s4], v5 = td2[s5], v6 = td2[s6], v7 = td2[s7];
        a0 += ((v0.y * fmaxf(fmaf(v0.x, w1.x, bv.x), 0.f)
              + v1.y * fmaxf(fmaf(v1.x, w1.x, bv.x), 0.f))
             + (v2.y * fmaxf(fmaf(v2.x, w1.x, bv.x), 0.f)
              + v3.y * fmaxf(fmaf(v3.x, w1.x, bv.x), 0.f)))
            + ((v4.y * fmaxf(fmaf(v4.x, w1.x, bv.x), 0.f)
              + v5.y * fmaxf(fmaf(v5.x, w1.x, bv.x), 0.f))
             + (v6.y * fmaxf(fmaf(v6.x, w1.x, bv.x), 0.f)
              + v7.y * fmaxf(fmaf(v7.x, w1.x, bv.x), 0.f)));
        a1 += ((v0.y * fmaxf(fmaf(v0.x, w1.y, bv.y), 0.f)
              + v1.y * fmaxf(fmaf(v1.x, w1.y, bv.y), 0.f))
             + (v2.y * fmaxf(fmaf(v2.x, w1.y, bv.y), 0.f)
              + v3.y * fmaxf(fmaf(v3.x, w1.y, bv.y), 0.f)))
            + ((v4.y * fmaxf(fmaf(v4.x, w1.y, bv.y), 0.f)
              + v5.y * fmaxf(fmaf(v5.x, w1.y, bv.y), 0.f))
             + (v6.y * fmaxf(fmaf(v6.x, w1.y, bv.y), 0.f)
              + v7.y * fmaxf(fmaf(v7.x, w1.y, bv.y), 0.f)));
        a2 += ((v0.y * fmaxf(fmaf(v0.x, w1.z, bv.z), 0.f)
              + v1.y * fmaxf(fmaf(v1.x, w1.z, bv.z), 0.f))
             + (v2.y * fmaxf(fmaf(v2.x, w1.z, bv.z), 0.f)
              + v3.y * fmaxf(fmaf(v3.x, w1.z, bv.z), 0.f)))
            + ((v4.y * fmaxf(fmaf(v4.x, w1.z, bv.z), 0.f)
              + v5.y * fmaxf(fmaf(v5.x, w1.z, bv.z), 0.f))
             + (v6.y * fmaxf(fmaf(v6.x, w1.z, bv.z), 0.f)
              + v7.y * fmaxf(fmaf(v7.x, w1.z, bv.z), 0.f)));
        a3 += ((v0.y * fmaxf(fmaf(v0.x, w1.w, bv.w), 0.f)
              + v1.y * fmaxf(fmaf(v1.x, w1.w, bv.w), 0.f))
             + (v2.y * fmaxf(fmaf(v2.x, w1.w, bv.w), 0.f)
              + v3.y * fmaxf(fmaf(v3.x, w1.w, bv.w), 0.f)))
            + ((v4.y * fmaxf(fmaf(v4.x, w1.w, bv.w), 0.f)
              + v5.y * fmaxf(fmaf(v5.x, w1.w, bv.w), 0.f))
             + (v6.y * fmaxf(fmaf(v6.x, w1.w, bv.w), 0.f)
              + v7.y * fmaxf(fmaf(v7.x, w1.w, bv.w), 0.f)));
    }
    for (; e < e1; ++e) {
        float2 v = td2[csr[e]];
        a0 += v.y * fmaxf(fmaf(v.x, w1.x, bv.x), 0.f);
        a1 += v.y * fmaxf(fmaf(v.x, w1.y, bv.y), 0.f);
        a2 += v.y * fmaxf(fmaf(v.x, w1.z, bv.z), 0.f);
        a3 += v.y * fmaxf(fmaf(v.x, w1.w, bv.w), 0.f);
    }
    out4[(size_t)node * 32 + lane] = make_float4(a0 * dd, a1 * dd, a2 * dd, a3 * dd);
}

// Half-row aggregation (F-split): out[d][half] = dis[d]*(sum hp[s][half] + hp[d][half])
__global__ void k_agg128h(const float4* __restrict__ hp4, const float* __restrict__ dis,
                          const int* __restrict__ row_ptr,
                          const unsigned short* __restrict__ csr,
                          float4* __restrict__ out4, int N, int half) {
    int node = blockIdx.x * 16 + (threadIdx.x >> 4);
    int lane = threadIdx.x & 15;
    if (node >= N) return;
    const int co = half * 16 + lane;           // column offset in float4 units
    float4 self = hp4[(size_t)node * 32 + co];
    float a0 = self.x, a1 = self.y, a2 = self.z, a3 = self.w;
    int e0 = row_ptr[node], e1 = row_ptr[node + 1];
    int e = e0;
    for (; e + 8 <= e1; e += 8) {
        int s0 = csr[e],     s1 = csr[e + 1], s2 = csr[e + 2], s3 = csr[e + 3];
        int s4 = csr[e + 4], s5 = csr[e + 5], s6 = csr[e + 6], s7 = csr[e + 7];
        float4 v0 = hp4[(size_t)s0 * 32 + co];
        float4 v1 = hp4[(size_t)s1 * 32 + co];
        float4 v2 = hp4[(size_t)s2 * 32 + co];
        float4 v3 = hp4[(size_t)s3 * 32 + co];
        float4 v4 = hp4[(size_t)s4 * 32 + co];
        float4 v5 = hp4[(size_t)s5 * 32 + co];
        float4 v6 = hp4[(size_t)s6 * 32 + co];
        float4 v7 = hp4[(size_t)s7 * 32 + co];
        a0 += ((v0.x + v1.x) + (v2.x + v3.x)) + ((v4.x + v5.x) + (v6.x + v7.x));
        a1 += ((v0.y + v1.y) + (v2.y + v3.y)) + ((v4.y + v5.y) + (v6.y + v7.y));
        a2 += ((v0.z + v1.z) + (v2.z + v3.z)) + ((v4.z + v5.z) + (v6.z + v7.z));
        a3 += ((v0.w + v1.w) + (v2.w + v3.w)) + ((v4.w + v5.w) + (v6.w + v7.w));
    }
    for (; e < e1; ++e) {
        int s = csr[e];
        float4 v = hp4[(size_t)s * 32 + co];
        a0 += v.x; a1 += v.y; a2 += v.z; a3 += v.w;
    }
    float d = dis[node];
    f32x4 r = {a0 * d, a1 * d, a2 * d, a3 * d};
    __builtin_nontemporal_store(r, (f32x4*)&out4[(size_t)node * 32 + co]);
}

// ---------------------------------------------------------------------------
// W prep + workspace zeroing, one dispatch (launched first in the stream)
__global__ void k_wpack2z(const float* __restrict__ W2, const float* __restrict__ W3,
                          unsigned short* __restrict__ Wp2H, unsigned short* __restrict__ Wp2L,
                          unsigned short* __restrict__ Wp3H, unsigned short* __restrict__ Wp3L,
                          int* __restrict__ deg, unsigned int* __restrict__ g, int N) {
    int idx = blockIdx.x * 256 + threadIdx.x;
    if (idx < N) deg[idx] = 0;
    if (idx < N_GRAPHS * 256) g[idx] = 0;
    const float* W; unsigned short *WpH, *WpL; int F, j;
    if (idx < 128 * 128) { W = W2; WpH = Wp2H; WpL = Wp2L; F = 128; j = idx; }
    else if (idx < 128 * 128 + 128 * 256) {
        W = W3; WpH = Wp3H; WpL = Wp3L; F = 256; j = idx - 128 * 128;
    } else return;
    int k = j / F, col = j - k * F;
    float v = W[j];
    unsigned short h = f2bf(v);
    unsigned short l = f2bf(v - bf2f(h));
    int o = ((k >> 3) * F + col) * 8 + (k & 7);
    WpH[o] = h; WpL[o] = l;
}

// MFMA GEMM (split-bf16, 4-term => fp32-level accuracy).
template<int FOUT, bool SCALE, bool FUSE_MAX>
__global__ __launch_bounds__(256, 3) void k_gemm_mfma(
        const float* __restrict__ A,
        const unsigned short* __restrict__ WpH, const unsigned short* __restrict__ WpL,
        const float* __restrict__ b, const float* __restrict__ dis,
        float* __restrict__ outp, const int* __restrict__ batch,
        unsigned int* __restrict__ gmax, int N) {
    __shared__ __align__(16) unsigned short ApH[4 * 4 * 16 * 8];  // [nt][kg][row][e]
    __shared__ __align__(16) unsigned short ApL[4 * 4 * 16 * 8];
    __shared__ __align__(16) unsigned short WlH[4 * 128 * 8];     // [kg][col][e]
    __shared__ __align__(16) unsigned short WlL[4 * 128 * 8];
    const int tid  = threadIdx.x;
    const int lane = tid & 63;
    const int w    = tid >> 6;        // wave id == node-tile nt
    const int n0   = blockIdx.x * 64;
    const int jh   = blockIdx.y;

    f32x4 acc[8];
#pragma unroll
    for (int ct = 0; ct < 8; ++ct) acc[ct] = (f32x4){0.f, 0.f, 0.f, 0.f};

    for (int kc = 0; kc < 128; kc += 32) {
        // ---- stage W (packed, linear copy) ----
#pragma unroll
        for (int it = 0; it < 2; ++it) {
            int q = tid + it * 256;                    // [0,512) f4 units
            int kg = q >> 7, cq = q & 127;
            int src = ((kc >> 3) + kg) * FOUT + jh * 128 + cq;
            ((f32x4*)WlH)[q] = ((const f32x4*)WpH)[src];
            ((f32x4*)WlL)[q] = ((const f32x4*)WpL)[src];
        }
        // ---- stage A (fp32 -> split bf16, packed) ----
#pragma unroll
        for (int it = 0; it < 2; ++it) {
            int idx = tid + it * 256;                  // [0,512)
            int node = idx >> 3, k4 = idx & 7;
            int gn = n0 + node;
            float4 a = (gn < N)
                ? *reinterpret_cast<const float4*>(A + (size_t)gn * 128 + kc + k4 * 4)
                : make_float4(0.f, 0.f, 0.f, 0.f);
            unsigned short h0 = f2bf(a.x), h1 = f2bf(a.y), h2 = f2bf(a.z), h3 = f2bf(a.w);
            unsigned short l0 = f2bf(a.x - bf2f(h0)), l1 = f2bf(a.y - bf2f(h1));
            unsigned short l2 = f2bf(a.z - bf2f(h2)), l3 = f2bf(a.w - bf2f(h3));
            int kg = k4 >> 1, e0 = (k4 & 1) * 4;
            int base = (((node >> 4) * 4 + kg) * 16 + (node & 15)) * 8 + e0;
            *reinterpret_cast<ushort4*>(&ApH[base]) = make_ushort4(h0, h1, h2, h3);
            *reinterpret_cast<ushort4*>(&ApL[base]) = make_ushort4(l0, l1, l2, l3);
        }
        __syncthreads();

        // ---- MFMA ----
        int aidx = (w * 4 + (lane >> 4)) * 16 + (lane & 15);
        bf16x8 aH = ((const bf16x8*)ApH)[aidx];
        bf16x8 aL = ((const bf16x8*)ApL)[aidx];
#pragma unroll
        for (int ct = 0; ct < 8; ++ct) {
            int bidx = (lane >> 4) * 128 + ct * 16 + (lane & 15);
            bf16x8 bH = ((const bf16x8*)WlH)[bidx];
            bf16x8 bL = ((const bf16x8*)WlL)[bidx];
            acc[ct] = __builtin_amdgcn_mfma_f32_16x16x32_bf16(aL, bL, acc[ct], 0, 0, 0);
            acc[ct] = __builtin_amdgcn_mfma_f32_16x16x32_bf16(aL, bH, acc[ct], 0, 0, 0);
            acc[ct] = __builtin_amdgcn_mfma_f32_16x16x32_bf16(aH, bL, acc[ct], 0, 0, 0);
            acc[ct] = __builtin_amdgcn_mfma_f32_16x16x32_bf16(aH, bH, acc[ct], 0, 0, 0);
        }
        __syncthreads();
    }

    // ---- epilogue: C/D layout col=lane&15, row=(lane>>4)*4+reg ----
    const int cl = lane & 15;
    const int r0 = (lane >> 4) * 4;
    float bb[8];
#pragma unroll
    for (int ct = 0; ct < 8; ++ct) bb[ct] = b[jh * 128 + ct * 16 + cl];

    if (!FUSE_MAX) {
#pragma unroll
        for (int r = 0; r < 4; ++r) {
            int node = n0 + w * 16 + r0 + r;
            if (node < N) {
                float dsc = SCALE ? dis[node] : 1.f;
                float* op = outp + (size_t)node * FOUT + jh * 128 + cl;
#pragma unroll
                for (int ct = 0; ct < 8; ++ct) {
                    float v = fmaxf(acc[ct][r] + bb[ct], 0.f);
                    op[ct * 16] = SCALE ? v * dsc : v;
                }
            }
        }
    } else {
        int nbm[4];
#pragma unroll
        for (int r = 0; r < 4; ++r) {
            int node = n0 + w * 16 + r0 + r;
            nbm[r] = (node < N) ? batch[node] : -1;
        }
        int gfirst = batch[n0];
        int glast  = batch[min(n0 + 63, N - 1)];
        for (int gb = gfirst; gb <= glast; ++gb) {
#pragma unroll
            for (int ct = 0; ct < 8; ++ct) {
                float m = 0.f;
#pragma unroll
                for (int r = 0; r < 4; ++r) {
                    float v = fmaxf(acc[ct][r] + bb[ct], 0.f);
                    if (nbm[r] == gb) m = fmaxf(m, v);
                }
                m = fmaxf(m, __shfl_xor(m, 16));
                m = fmaxf(m, __shfl_xor(m, 32));
                if ((lane >> 4) == 0)
                    atomicMax(&gmax[gb * 256 + jh * 128 + ct * 16 + cl],
                              __float_as_uint(m));
            }
        }
    }
}

// final MLP: out = relu( relu(g@Wf1+bf1) @ Wf2 + bf2 )
__global__ void k_mlp(const float* __restrict__ g, const float* __restrict__ Wf1,
                      const float* __restrict__ bf1, const float* __restrict__ Wf2,
                      const float* __restrict__ bf2, float* __restrict__ out) {
    __shared__ float gr[256];
    __shared__ float g1s[128];
    const int gid = blockIdx.x;
    const int tid = threadIdx.x;
    gr[tid] = g[gid * 256 + tid];
    gr[tid + 128] = g[gid * 256 + 128 + tid];
    __syncthreads();
    float acc = bf1[tid];
    for (int k = 0; k < 256; ++k)
        acc = fmaf(gr[k], Wf1[k * 128 + tid], acc);
    g1s[tid] = fmaxf(acc, 0.f);
    __syncthreads();
    if (tid < 10) {
        float a = bf2[tid];
        for (int k = 0; k < 128; ++k)
            a = fmaf(g1s[k], Wf2[k * 10 + tid], a);
        out[gid * 10 + tid] = fmaxf(a, 0.f);
    }
}

// ---------------------------------------------------------------------------
extern "C" void kernel_launch(void* const* d_in, const int* in_sizes, int n_in,
                              void* d_out, int out_size, void* d_ws, size_t ws_size,
                              hipStream_t stream) {
    const float* x   = (const float*)d_in[0];
    const int*   ei  = (const int*)d_in[1];
    const int*   bat = (const int*)d_in[2];
    const float* W1  = (const float*)d_in[3];
    const float* b1  = (const float*)d_in[4];
    const float* W2  = (const float*)d_in[5];
    const float* b2  = (const float*)d_in[6];
    const float* W3  = (const float*)d_in[7];
    const float* b3  = (const float*)d_in[8];
    const float* Wf1 = (const float*)d_in[9];
    const float* bf1 = (const float*)d_in[10];
    const float* Wf2 = (const float*)d_in[11];
    const float* bf2 = (const float*)d_in[12];
    float* out = (float*)d_out;

    const int N = in_sizes[0];          // 50000
    const int E = in_sizes[1] / 2;      // 800000
    const int* src = ei;
    const int* dst = ei + E;

    char* base = (char*)d_ws;
    size_t off = 0;
    auto carve = [&](size_t bytes) -> char* {
        char* p = base + off;
        off = (off + bytes + 255) & ~(size_t)255;
        return p;
    };
    const int nb = (N + 255) / 256;
    int*    deg     = (int*)   carve((size_t)N * 4);
    unsigned short* epos = (unsigned short*)carve((size_t)E * 2);
    int*    row_ptr = (int*)   carve((size_t)(N + 1) * 4);
    unsigned short* csr = (unsigned short*)carve((size_t)E * 2);
    float*  dis     = (float*) carve((size_t)N * 4);
    float*  xp      = (float*) carve((size_t)N * 4);
    float2* td2     = (float2*)carve((size_t)N * 8);
    float*  A2      = (float*) carve((size_t)N * 128 * 4);
    float*  B2      = (float*) carve((size_t)N * 128 * 4);
    float*  A3      = (float*) carve((size_t)N * 128 * 4);
    unsigned int* g = (unsigned int*)carve((size_t)N_GRAPHS * 256 * 4);
    int*    bsum    = (int*)   carve((size_t)nb * 4);
    int*    boff    = (int*)   carve((size_t)nb * 4);
    unsigned short* Wp2H = (unsigned short*)carve((size_t)128 * 128 * 2);
    unsigned short* Wp2L = (unsigned short*)carve((size_t)128 * 128 * 2);
    unsigned short* Wp3H = (unsigned short*)carve((size_t)128 * 256 * 2);
    unsigned short* Wp3L = (unsigned short*)carve((size_t)128 * 256 * 2);
    (void)ws_size; (void)n_in; (void)out_size;

    int eb = (E + 255) / 256;

    // W split+pack + zero deg/g (one dispatch, replaces both memsets)
    k_wpack2z<<<nb, 256, 0, stream>>>(W2, W3, Wp2H, Wp2L, Wp3H, Wp3L, deg, g, N);

    // CSR build: ONE atomic pass (deg+pos16), scan, then atomic-free placement
    k_degpos<<<eb, 256, 0, stream>>>(dst, E, deg, epos);
    k_dis_bsum<<<nb, 256, 0, stream>>>(deg, x, dis, xp, bsum, N);
    k_scan_sums<<<1, 256, 0, stream>>>(bsum, nb, boff);
    k_scan_apply<<<nb, 256, 0, stream>>>(deg, boff, row_ptr, N);
    k_place<<<eb, 256, 0, stream>>>(src, dst, epos, row_ptr, E, csr);

    k_agg_scalar<<<nb, 256, 0, stream>>>(xp, dis, row_ptr, csr, td2, N);

    const int gx = (N + 63) / 64;
    const int ab = (N + 7) / 8;
    const int ab16 = (N + 15) / 16;

    // layer 1+2: recompute-gather h1 -> A2 (LDS-free), then MFMA GEMM W2 -> B2
    k_h1agg<<<ab, 256, 0, stream>>>(td2, (const float4*)W1, (const float4*)b1,
                                    row_ptr, csr, (float4*)A2, N);
    k_gemm_mfma<128, true, false><<<dim3(gx, 1), 256, 0, stream>>>(
        A2, Wp2H, Wp2L, b2, dis, B2, nullptr, nullptr, N);

    // layer 3: F-split row-gather aggregation (two 12.8MB slabs), then
    // MFMA GEMM W3 + fused max-pool
    k_agg128h<<<ab16, 256, 0, stream>>>((const float4*)B2, dis, row_ptr, csr,
                                        (float4*)A3, N, 0);
    k_agg128h<<<ab16, 256, 0, stream>>>((const float4*)B2, dis, row_ptr, csr,
                                        (float4*)A3, N, 1);
    k_gemm_mfma<256, false, true><<<dim3(gx, 2), 256, 0, stream>>>(
        A3, Wp3H, Wp3L, b3, nullptr, nullptr, bat, g, N);

    k_mlp<<<N_GRAPHS, 128, 0, stream>>>((const float*)g, Wf1, bf1, Wf2, bf2, out);
}